// Round 1
// baseline (3235.076 us; speedup 1.0000x reference)
//
#include <hip/hip_runtime.h>

// SiameseClassifier: twin LSTM (shared weights) over T=128 steps, B=128 each,
// E=H=1024, V=32000. out[b] = exp(-L1(h_a[b], h_b[b])).
//
// Structure:
//   prep_w:     cast [w_ih | w_hh] -> Wc bf16 [4096][2048]
//   prep_state: bias = b_ih + b_hh; h0/c0 -> state bufs; gather x_0
//   lstm_step ×128: fused GEMM [256,2048]@[2048,4096](bf16 MFMA) + cell update
//               + pre-gather of x_{t+1} (by the m==0 blocks)
//   finalize:   out[b] = exp(-sum_j |h[b][j] - h[b+128][j]|)

typedef unsigned short u16;
typedef __attribute__((ext_vector_type(8))) unsigned short u16x8;
typedef __attribute__((ext_vector_type(4))) unsigned short u16x4;
typedef __attribute__((ext_vector_type(8))) short s16x8;
typedef __attribute__((ext_vector_type(4))) float f32x4;

__device__ __forceinline__ u16 f2bf(float f) {
  unsigned int u = __builtin_bit_cast(unsigned int, f);
  u += 0x7fffu + ((u >> 16) & 1u);   // RNE
  return (u16)(u >> 16);
}
__device__ __forceinline__ float bf2f(u16 x) {
  unsigned int u = ((unsigned int)x) << 16;
  return __builtin_bit_cast(float, u);
}

// ---------------- prep: weights ----------------
// Wc[j][k] = k<1024 ? w_ih[j][k] : w_hh[j][k-1024], bf16. 4096x2048 elems.
__global__ __launch_bounds__(256) void prep_w_kernel(const float* __restrict__ w_ih,
                                                     const float* __restrict__ w_hh,
                                                     u16* __restrict__ Wc) {
  for (unsigned idx = blockIdx.x * 256u + threadIdx.x; idx < 2097152u; idx += 524288u) {
    unsigned e4 = idx * 4u;
    unsigned j = e4 >> 11;
    unsigned k = e4 & 2047u;
    const float* src = (k < 1024u) ? (w_ih + (size_t)j * 1024u + k)
                                   : (w_hh + (size_t)j * 1024u + (k - 1024u));
    float4 v = *(const float4*)src;
    u16x4 o;
    o[0] = f2bf(v.x); o[1] = f2bf(v.y); o[2] = f2bf(v.z); o[3] = f2bf(v.w);
    *(u16x4*)(Wc + (size_t)j * 2048u + k) = o;
  }
}

// ---------------- prep: state ----------------
// grid 1024 x 256 = 262144 threads, one elem each over [256][1024]
__global__ __launch_bounds__(256) void prep_state_kernel(
    const float* __restrict__ h0a, const float* __restrict__ h0b,
    const float* __restrict__ c0a, const float* __restrict__ c0b,
    const float* __restrict__ b_ih, const float* __restrict__ b_hh,
    const int* __restrict__ batch_a, const int* __restrict__ batch_b,
    const float* __restrict__ emb,
    float* __restrict__ bias, u16* __restrict__ hb0, float* __restrict__ cb,
    u16* __restrict__ xb0) {
  unsigned i = blockIdx.x * 256u + threadIdx.x;
  unsigned r = i >> 10;
  unsigned k = i & 1023u;
  float hv = (r < 128u) ? h0a[i] : h0b[i - 131072u];
  float cv = (r < 128u) ? c0a[i] : c0b[i - 131072u];
  hb0[i] = f2bf(hv);
  cb[i] = cv;
  int token = (r < 128u) ? batch_a[r] : batch_b[r - 128u];
  xb0[i] = f2bf(emb[(size_t)token * 1024u + k]);
  if (i < 4096u) bias[i] = b_ih[i] + b_hh[i];
}

// ---------------- the recurrent step ----------------
// grid 256 = 4 M-tiles (64 batch rows) x 64 NH-tiles (16 h-units = 64 gate cols)
// block 256 thr = 4 waves (2x2 of 32x32), mfma 16x16x32 bf16, K = 2048, KSTEP 64.
__global__ __launch_bounds__(256) void lstm_step_kernel(
    const int* __restrict__ batch_a, const int* __restrict__ batch_b,
    const float* __restrict__ emb, const u16* __restrict__ Wc,
    const float* __restrict__ bias,
    const u16* __restrict__ x_in, u16* __restrict__ x_next,
    const u16* __restrict__ h_in, u16* __restrict__ h_out,
    float* __restrict__ cbuf, int t) {
  __shared__ u16 As[64][72];     // batch rows x K-chunk (pad 8 -> 2-way free)
  __shared__ u16 Bs[64][72];     // gate cols  x K-chunk
  __shared__ float Gs[64][68];   // gates remix for the cell update

  const int tid = threadIdx.x;
  const int lane = tid & 63;
  const int w = tid >> 6;
  const int wm = w >> 1, wn = w & 1;
  const int m = blockIdx.x >> 6;    // 0..3   (XCD = bx%8 keyed by nh -> W stays L2-resident)
  const int nh = blockIdx.x & 63;   // 0..63

  // staging: each thread loads 16 elems of A and 16 of B per K-step
  const int srow = tid >> 2;        // 0..63
  const int scol = (tid & 3) << 4;  // 0,16,32,48

  const int R = m * 64 + srow;
  const u16* aX = x_in + (size_t)R * 1024;
  const u16* aH = h_in + (size_t)R * 1024;
  const int bq = srow >> 4;         // gate strip of this B-row
  const u16* bW = Wc + ((size_t)(bq * 1024 + nh * 16 + (srow & 15))) * 2048;

  f32x4 acc[2][2];
#pragma unroll
  for (int a_ = 0; a_ < 2; ++a_)
#pragma unroll
    for (int b_ = 0; b_ < 2; ++b_) acc[a_][b_] = (f32x4){0.f, 0.f, 0.f, 0.f};

  const int fr = lane & 15;          // fragment row (A) / col (B)
  const int fk = (lane >> 4) << 3;   // k sub-offset: 0,8,16,24

  for (int k0 = 0; k0 < 2048; k0 += 64) {
    const u16* asrc = (k0 < 1024) ? (aX + k0 + scol) : (aH + (k0 - 1024) + scol);
    u16x8 av0 = *(const u16x8*)asrc;
    u16x8 av1 = *(const u16x8*)(asrc + 8);
    u16x8 bv0 = *(const u16x8*)(bW + k0 + scol);
    u16x8 bv1 = *(const u16x8*)(bW + k0 + scol + 8);
    __syncthreads();                      // prev iter's frag reads done
    *(u16x8*)&As[srow][scol] = av0;
    *(u16x8*)&As[srow][scol + 8] = av1;
    *(u16x8*)&Bs[srow][scol] = bv0;
    *(u16x8*)&Bs[srow][scol + 8] = bv1;
    __syncthreads();
#pragma unroll
    for (int kc = 0; kc < 64; kc += 32) {
      s16x8 af0 = *(const s16x8*)&As[wm * 32 + fr][kc + fk];
      s16x8 af1 = *(const s16x8*)&As[wm * 32 + 16 + fr][kc + fk];
      s16x8 bf0 = *(const s16x8*)&Bs[wn * 32 + fr][kc + fk];
      s16x8 bf1 = *(const s16x8*)&Bs[wn * 32 + 16 + fr][kc + fk];
      acc[0][0] = __builtin_amdgcn_mfma_f32_16x16x32_bf16(af0, bf0, acc[0][0], 0, 0, 0);
      acc[0][1] = __builtin_amdgcn_mfma_f32_16x16x32_bf16(af0, bf1, acc[0][1], 0, 0, 0);
      acc[1][0] = __builtin_amdgcn_mfma_f32_16x16x32_bf16(af1, bf0, acc[1][0], 0, 0, 0);
      acc[1][1] = __builtin_amdgcn_mfma_f32_16x16x32_bf16(af1, bf1, acc[1][1], 0, 0, 0);
    }
  }

  // spill gates to LDS for the i/f/g/o remix
#pragma unroll
  for (int a_ = 0; a_ < 2; ++a_)
#pragma unroll
    for (int b_ = 0; b_ < 2; ++b_)
#pragma unroll
      for (int r_ = 0; r_ < 4; ++r_)
        Gs[wm * 32 + a_ * 16 + ((lane >> 4) << 2) + r_][wn * 32 + b_ * 16 + fr] =
            acc[a_][b_][r_];
  __syncthreads();

  // cell update: 64 rows x 16 units, 4 per thread. Block-local gate col = q*16+u.
  {
    const int row = tid >> 2;
    const int R2 = m * 64 + row;
    const int u0 = (tid & 3) << 2;
#pragma unroll
    for (int uu = 0; uu < 4; ++uu) {
      int u = u0 + uu;
      int gj = nh * 16 + u;                 // global h-unit
      float iv = Gs[row][u]      + bias[gj];
      float fv = Gs[row][16 + u] + bias[1024 + gj];
      float gv = Gs[row][32 + u] + bias[2048 + gj];
      float ov = Gs[row][48 + u] + bias[3072 + gj];
      size_t ci = (size_t)R2 * 1024 + gj;
      float c_old = cbuf[ci];
      float si = 1.f / (1.f + __expf(-iv));
      float sf = 1.f / (1.f + __expf(-fv));
      float so = 1.f / (1.f + __expf(-ov));
      float cn = sf * c_old + si * tanhf(gv);
      float hn = so * tanhf(cn);
      cbuf[ci] = cn;                         // c updated in place (unique owner)
      h_out[ci] = f2bf(hn);
    }
  }

  // pre-gather x_{t+1} (dense bf16) so next step's GEMM reads L2, not emb gathers
  if (m == 0 && t + 1 < 128) {
#pragma unroll
    for (int rr = 0; rr < 4; ++rr) {
      int r = nh * 4 + rr;
      int token = (r < 128) ? batch_a[(t + 1) * 128 + r]
                            : batch_b[(t + 1) * 128 + (r - 128)];
      const float* esrc = emb + (size_t)token * 1024;
      u16* dst = x_next + (size_t)r * 1024;
      int c = tid * 4;
      float4 v = *(const float4*)(esrc + c);
      u16x4 o;
      o[0] = f2bf(v.x); o[1] = f2bf(v.y); o[2] = f2bf(v.z); o[3] = f2bf(v.w);
      *(u16x4*)(dst + c) = o;
    }
  }
}

// ---------------- finalize ----------------
__global__ __launch_bounds__(256) void finalize_kernel(const u16* __restrict__ h,
                                                       float* __restrict__ out) {
  int b = blockIdx.x;
  int tid = threadIdx.x;
  const u16* ha = h + (size_t)b * 1024;
  const u16* hb = h + (size_t)(b + 128) * 1024;
  float s = 0.f;
  for (int j = tid; j < 1024; j += 256) s += fabsf(bf2f(ha[j]) - bf2f(hb[j]));
  __shared__ float red[256];
  red[tid] = s;
  __syncthreads();
  for (int off = 128; off > 0; off >>= 1) {
    if (tid < off) red[tid] += red[tid + off];
    __syncthreads();
  }
  if (tid == 0) out[b] = expf(-red[0]);
}

extern "C" void kernel_launch(void* const* d_in, const int* in_sizes, int n_in,
                              void* d_out, int out_size, void* d_ws, size_t ws_size,
                              hipStream_t stream) {
  const int* batch_a = (const int*)d_in[0];
  const int* batch_b = (const int*)d_in[1];
  const float* h0_a = (const float*)d_in[2];
  const float* c0_a = (const float*)d_in[3];
  const float* h0_b = (const float*)d_in[4];
  const float* c0_b = (const float*)d_in[5];
  const float* emb  = (const float*)d_in[6];
  const float* w_ih = (const float*)d_in[7];
  const float* w_hh = (const float*)d_in[8];
  const float* b_ih = (const float*)d_in[9];
  const float* b_hh = (const float*)d_in[10];

  char* ws = (char*)d_ws;
  // layout (all 16B-aligned):
  u16*   Wc   = (u16*)(ws);                    // 16,777,216 B
  float* bias = (float*)(ws + 16777216);       //     16,384 B
  u16*   xb0  = (u16*)(ws + 16793600);         //    524,288 B
  u16*   xb1  = (u16*)(ws + 17317888);         //    524,288 B
  u16*   hb0  = (u16*)(ws + 17842176);         //    524,288 B
  u16*   hb1  = (u16*)(ws + 18366464);         //    524,288 B
  float* cb   = (float*)(ws + 18890752);       //  1,048,576 B  (end ~19.94 MB)

  prep_w_kernel<<<2048, 256, 0, stream>>>(w_ih, w_hh, Wc);
  prep_state_kernel<<<1024, 256, 0, stream>>>(h0_a, h0_b, c0_a, c0_b, b_ih, b_hh,
                                              batch_a, batch_b, emb, bias, hb0, cb, xb0);
  u16* xb[2] = {xb0, xb1};
  u16* hb[2] = {hb0, hb1};
  for (int t = 0; t < 128; ++t) {
    lstm_step_kernel<<<256, 256, 0, stream>>>(batch_a, batch_b, emb, Wc, bias,
                                              xb[t & 1], xb[(t + 1) & 1],
                                              hb[t & 1], hb[(t + 1) & 1], cb, t);
  }
  finalize_kernel<<<128, 256, 0, stream>>>(hb[0], (float*)d_out);
}

// Round 2
// 2431.541 us; speedup vs baseline: 1.3305x; 1.3305x over previous
//
#include <hip/hip_runtime.h>

// SiameseClassifier: twin LSTM (shared weights) over T=128 steps, B=128 each,
// E=H=1024, V=32000. out[b] = exp(-L1(h_a[b], h_b[b])).
//
// R1: 512-thread blocks (8 waves = 2/SIMD for latency hiding), K split between
// two wave-groups (x-half / h-half), KSTEP=128 (fewer barriers), global->reg
// prefetch pipelined under MFMA compute.

typedef unsigned short u16;
typedef __attribute__((ext_vector_type(8))) unsigned short u16x8;
typedef __attribute__((ext_vector_type(4))) unsigned short u16x4;
typedef __attribute__((ext_vector_type(8))) short s16x8;
typedef __attribute__((ext_vector_type(4))) float f32x4;

__device__ __forceinline__ u16 f2bf(float f) {
  unsigned int u = __builtin_bit_cast(unsigned int, f);
  u += 0x7fffu + ((u >> 16) & 1u);   // RNE
  return (u16)(u >> 16);
}
__device__ __forceinline__ float bf2f(u16 x) {
  unsigned int u = ((unsigned int)x) << 16;
  return __builtin_bit_cast(float, u);
}

// ---------------- prep: weights ----------------
// Wc[j][k] = k<1024 ? w_ih[j][k] : w_hh[j][k-1024], bf16. 4096x2048 elems.
__global__ __launch_bounds__(256) void prep_w_kernel(const float* __restrict__ w_ih,
                                                     const float* __restrict__ w_hh,
                                                     u16* __restrict__ Wc) {
  for (unsigned idx = blockIdx.x * 256u + threadIdx.x; idx < 2097152u; idx += 524288u) {
    unsigned e4 = idx * 4u;
    unsigned j = e4 >> 11;
    unsigned k = e4 & 2047u;
    const float* src = (k < 1024u) ? (w_ih + (size_t)j * 1024u + k)
                                   : (w_hh + (size_t)j * 1024u + (k - 1024u));
    float4 v = *(const float4*)src;
    u16x4 o;
    o[0] = f2bf(v.x); o[1] = f2bf(v.y); o[2] = f2bf(v.z); o[3] = f2bf(v.w);
    *(u16x4*)(Wc + (size_t)j * 2048u + k) = o;
  }
}

// ---------------- prep: state ----------------
__global__ __launch_bounds__(256) void prep_state_kernel(
    const float* __restrict__ h0a, const float* __restrict__ h0b,
    const float* __restrict__ c0a, const float* __restrict__ c0b,
    const float* __restrict__ b_ih, const float* __restrict__ b_hh,
    const int* __restrict__ batch_a, const int* __restrict__ batch_b,
    const float* __restrict__ emb,
    float* __restrict__ bias, u16* __restrict__ hb0, float* __restrict__ cb,
    u16* __restrict__ xb0) {
  unsigned i = blockIdx.x * 256u + threadIdx.x;
  unsigned r = i >> 10;
  unsigned k = i & 1023u;
  float hv = (r < 128u) ? h0a[i] : h0b[i - 131072u];
  float cv = (r < 128u) ? c0a[i] : c0b[i - 131072u];
  hb0[i] = f2bf(hv);
  cb[i] = cv;
  int token = (r < 128u) ? batch_a[r] : batch_b[r - 128u];
  xb0[i] = f2bf(emb[(size_t)token * 1024u + k]);
  if (i < 4096u) bias[i] = b_ih[i] + b_hh[i];
}

// ---------------- the recurrent step ----------------
// grid 256 = 4 M-tiles (64 batch rows) x 64 NH-tiles (16 h-units = 64 gate cols)
// block 512 = 8 waves: (wm,wn) 2x2 output sub-tiles x kg 2 K-groups.
// Group kg handles K range [kg*1024, kg*1024+1024) in 8 iters of KSTEP=128.
__global__ __launch_bounds__(512) void lstm_step_kernel(
    const int* __restrict__ batch_a, const int* __restrict__ batch_b,
    const float* __restrict__ emb, const u16* __restrict__ Wc,
    const float* __restrict__ bias,
    const u16* __restrict__ x_in, u16* __restrict__ x_next,
    const u16* __restrict__ h_in, u16* __restrict__ h_out,
    float* __restrict__ cbuf, int t) {
  __shared__ u16 As[2][64][136];   // row stride 272B = 17 granules (odd -> ~2-way, free)
  __shared__ u16 Bs[2][64][136];
  __shared__ float Gs[64][68];

  const int tid = threadIdx.x;
  const int lane = tid & 63;
  const int w = tid >> 6;
  const int wm = (w >> 1) & 1, wn = w & 1, kg = w >> 2;
  const int m = blockIdx.x >> 6;    // 0..3  (XCD = bx%8 keyed by nh -> W L2-resident)
  const int nh = blockIdx.x & 63;   // 0..63

  // staging: group = 256 threads; each thread 32 consecutive elems of A and B
  const int gtid = tid & 255;
  const int srow = gtid >> 2;        // 0..63
  const int scol = (gtid & 3) << 5;  // 0,32,64,96

  const int R = m * 64 + srow;
  const u16* aBase = (kg == 0 ? x_in : h_in) + (size_t)R * 1024 + scol;
  const u16* bBase = Wc + ((size_t)((srow >> 4) * 1024 + nh * 16 + (srow & 15))) * 2048
                        + kg * 1024 + scol;

  f32x4 acc[2][2];
#pragma unroll
  for (int a_ = 0; a_ < 2; ++a_)
#pragma unroll
    for (int b_ = 0; b_ < 2; ++b_) acc[a_][b_] = (f32x4){0.f, 0.f, 0.f, 0.f};

  const int fr = lane & 15;          // fragment row (A) / col (B)
  const int fk = (lane >> 4) << 3;   // k sub-offset: 0,8,16,24

  u16x8 ar[4], br[4];
#pragma unroll
  for (int q = 0; q < 4; ++q) {
    ar[q] = *(const u16x8*)(aBase + q * 8);
    br[q] = *(const u16x8*)(bBase + q * 8);
  }

  for (int it = 0; it < 8; ++it) {
    __syncthreads();                  // prev iter's frag reads done
#pragma unroll
    for (int q = 0; q < 4; ++q) {
      *(u16x8*)&As[kg][srow][scol + q * 8] = ar[q];
      *(u16x8*)&Bs[kg][srow][scol + q * 8] = br[q];
    }
    __syncthreads();
    if (it + 1 < 8) {                 // prefetch next tile; latency hides under MFMAs
      const u16* an = aBase + (it + 1) * 128;
      const u16* bn = bBase + (it + 1) * 128;
#pragma unroll
      for (int q = 0; q < 4; ++q) {
        ar[q] = *(const u16x8*)(an + q * 8);
        br[q] = *(const u16x8*)(bn + q * 8);
      }
    }
#pragma unroll
    for (int kc = 0; kc < 128; kc += 32) {
      s16x8 af0 = *(const s16x8*)&As[kg][wm * 32 + fr][kc + fk];
      s16x8 af1 = *(const s16x8*)&As[kg][wm * 32 + 16 + fr][kc + fk];
      s16x8 bf0 = *(const s16x8*)&Bs[kg][wn * 32 + fr][kc + fk];
      s16x8 bf1 = *(const s16x8*)&Bs[kg][wn * 32 + 16 + fr][kc + fk];
      acc[0][0] = __builtin_amdgcn_mfma_f32_16x16x32_bf16(af0, bf0, acc[0][0], 0, 0, 0);
      acc[0][1] = __builtin_amdgcn_mfma_f32_16x16x32_bf16(af0, bf1, acc[0][1], 0, 0, 0);
      acc[1][0] = __builtin_amdgcn_mfma_f32_16x16x32_bf16(af1, bf0, acc[1][0], 0, 0, 0);
      acc[1][1] = __builtin_amdgcn_mfma_f32_16x16x32_bf16(af1, bf1, acc[1][1], 0, 0, 0);
    }
  }

  // combine the two K-group partials through Gs, then cell update
  if (kg == 0) {
#pragma unroll
    for (int a_ = 0; a_ < 2; ++a_)
#pragma unroll
      for (int b_ = 0; b_ < 2; ++b_)
#pragma unroll
        for (int r_ = 0; r_ < 4; ++r_)
          Gs[wm * 32 + a_ * 16 + ((lane >> 4) << 2) + r_][wn * 32 + b_ * 16 + fr] =
              acc[a_][b_][r_];
  }
  __syncthreads();
  if (kg == 1) {
#pragma unroll
    for (int a_ = 0; a_ < 2; ++a_)
#pragma unroll
      for (int b_ = 0; b_ < 2; ++b_)
#pragma unroll
        for (int r_ = 0; r_ < 4; ++r_)
          Gs[wm * 32 + a_ * 16 + ((lane >> 4) << 2) + r_][wn * 32 + b_ * 16 + fr] +=
              acc[a_][b_][r_];
  }
  __syncthreads();

  // cell update: 64 rows x 16 units; 512 threads -> 2 units each
  {
    const int row = tid >> 3;
    const int R2 = m * 64 + row;
    const int u0 = (tid & 7) << 1;
#pragma unroll
    for (int uu = 0; uu < 2; ++uu) {
      int u = u0 + uu;
      int gj = nh * 16 + u;                 // global h-unit
      float iv = Gs[row][u]      + bias[gj];
      float fv = Gs[row][16 + u] + bias[1024 + gj];
      float gv = Gs[row][32 + u] + bias[2048 + gj];
      float ov = Gs[row][48 + u] + bias[3072 + gj];
      size_t ci = (size_t)R2 * 1024 + gj;
      float c_old = cbuf[ci];
      float si = 1.f / (1.f + __expf(-iv));
      float sf = 1.f / (1.f + __expf(-fv));
      float so = 1.f / (1.f + __expf(-ov));
      float cn = sf * c_old + si * tanhf(gv);
      float hn = so * tanhf(cn);
      cbuf[ci] = cn;                         // c updated in place (unique owner)
      h_out[ci] = f2bf(hn);
    }
  }

  // pre-gather x_{t+1} (dense bf16) so next step's GEMM reads L2, not emb gathers
  if (m == 0 && t + 1 < 128) {
    int r = nh * 4 + (tid >> 7);            // 4 rows per block, 64 blocks -> 256 rows
    int token = (r < 128) ? batch_a[(t + 1) * 128 + r]
                          : batch_b[(t + 1) * 128 + (r - 128)];
    const float* esrc = emb + (size_t)token * 1024 + (size_t)((tid & 127) * 8);
    float4 v0 = *(const float4*)esrc;
    float4 v1 = *(const float4*)(esrc + 4);
    u16x8 o;
    o[0] = f2bf(v0.x); o[1] = f2bf(v0.y); o[2] = f2bf(v0.z); o[3] = f2bf(v0.w);
    o[4] = f2bf(v1.x); o[5] = f2bf(v1.y); o[6] = f2bf(v1.z); o[7] = f2bf(v1.w);
    *(u16x8*)(x_next + (size_t)r * 1024 + (size_t)((tid & 127) * 8)) = o;
  }
}

// ---------------- finalize ----------------
__global__ __launch_bounds__(256) void finalize_kernel(const u16* __restrict__ h,
                                                       float* __restrict__ out) {
  int b = blockIdx.x;
  int tid = threadIdx.x;
  const u16* ha = h + (size_t)b * 1024;
  const u16* hb = h + (size_t)(b + 128) * 1024;
  float s = 0.f;
  for (int j = tid; j < 1024; j += 256) s += fabsf(bf2f(ha[j]) - bf2f(hb[j]));
  __shared__ float red[256];
  red[tid] = s;
  __syncthreads();
  for (int off = 128; off > 0; off >>= 1) {
    if (tid < off) red[tid] += red[tid + off];
    __syncthreads();
  }
  if (tid == 0) out[b] = expf(-red[0]);
}

extern "C" void kernel_launch(void* const* d_in, const int* in_sizes, int n_in,
                              void* d_out, int out_size, void* d_ws, size_t ws_size,
                              hipStream_t stream) {
  const int* batch_a = (const int*)d_in[0];
  const int* batch_b = (const int*)d_in[1];
  const float* h0_a = (const float*)d_in[2];
  const float* c0_a = (const float*)d_in[3];
  const float* h0_b = (const float*)d_in[4];
  const float* c0_b = (const float*)d_in[5];
  const float* emb  = (const float*)d_in[6];
  const float* w_ih = (const float*)d_in[7];
  const float* w_hh = (const float*)d_in[8];
  const float* b_ih = (const float*)d_in[9];
  const float* b_hh = (const float*)d_in[10];

  char* ws = (char*)d_ws;
  u16*   Wc   = (u16*)(ws);                    // 16,777,216 B
  float* bias = (float*)(ws + 16777216);       //     16,384 B
  u16*   xb0  = (u16*)(ws + 16793600);         //    524,288 B
  u16*   xb1  = (u16*)(ws + 17317888);         //    524,288 B
  u16*   hb0  = (u16*)(ws + 17842176);         //    524,288 B
  u16*   hb1  = (u16*)(ws + 18366464);         //    524,288 B
  float* cb   = (float*)(ws + 18890752);       //  1,048,576 B

  prep_w_kernel<<<2048, 256, 0, stream>>>(w_ih, w_hh, Wc);
  prep_state_kernel<<<1024, 256, 0, stream>>>(h0_a, h0_b, c0_a, c0_b, b_ih, b_hh,
                                              batch_a, batch_b, emb, bias, hb0, cb, xb0);
  u16* xb[2] = {xb0, xb1};
  u16* hb[2] = {hb0, hb1};
  for (int t = 0; t < 128; ++t) {
    lstm_step_kernel<<<256, 512, 0, stream>>>(batch_a, batch_b, emb, Wc, bias,
                                              xb[t & 1], xb[(t + 1) & 1],
                                              hb[t & 1], hb[(t + 1) & 1], cb, t);
  }
  finalize_kernel<<<128, 256, 0, stream>>>(hb[0], (float*)d_out);
}

// Round 3
// 1745.423 us; speedup vs baseline: 1.8535x; 1.3931x over previous
//
#include <hip/hip_runtime.h>

// SiameseClassifier: twin LSTM (shared weights) over T=128 steps, B=128 each,
// E=H=1024, V=32000. out[b] = exp(-L1(h_a[b], h_b[b])).
//
// R3: LDS-conflict elimination.
//  - W pre-swizzled into MFMA fragment order (Wf): B-frags load global(L2)->VGPR,
//    no Bs LDS tile at all.
//  - A tile: unpadded 256B rows + XOR swizzle (byte ^= (row&7)<<4); staging map
//    gives exactly 8 dwords/bank on writes AND reads (LDS floor).
//  - As double-buffered -> 1 barrier per K-step (8 total in main loop).
//  - x_{t+1} gather spread over all 256 blocks (1 row each), loads issued at
//    kernel top, stored at the end.

typedef unsigned short u16;
typedef __attribute__((ext_vector_type(8))) unsigned short u16x8;
typedef __attribute__((ext_vector_type(8))) short s16x8;
typedef __attribute__((ext_vector_type(4))) float f32x4;

__device__ __forceinline__ u16 f2bf(float f) {
  unsigned int u = __builtin_bit_cast(unsigned int, f);
  u += 0x7fffu + ((u >> 16) & 1u);   // RNE
  return (u16)(u >> 16);
}
__device__ __forceinline__ float bf2f(u16 x) {
  unsigned int u = ((unsigned int)x) << 16;
  return __builtin_bit_cast(float, u);
}

// ---------------- prep: weights into fragment order ----------------
// Wf flat idx = (((nh*4 + f)*64 + kc)*64 + lane)*8 + j
//   element: W_row[f*1024 + nh*16 + (lane&15)], k = kc*32 + (lane>>4)*8 + j
//   where W_row[r][k] = k<1024 ? w_ih[r][k] : w_hh[r][k-1024]
__global__ __launch_bounds__(256) void prep_wf_kernel(const float* __restrict__ w_ih,
                                                      const float* __restrict__ w_hh,
                                                      u16* __restrict__ Wf) {
  unsigned idx = blockIdx.x * 256u + threadIdx.x;          // 0..1048575
  unsigned l = idx & 63u;
  unsigned kc = (idx >> 6) & 63u;
  unsigned f = (idx >> 12) & 3u;
  unsigned nh = idx >> 14;
  unsigned r = f * 1024u + nh * 16u + (l & 15u);
  unsigned k0 = kc * 32u + ((l >> 4) << 3);
  const float* src = (k0 < 1024u) ? (w_ih + (size_t)r * 1024u + k0)
                                  : (w_hh + (size_t)r * 1024u + (k0 - 1024u));
  float4 v0 = *(const float4*)src;
  float4 v1 = *(const float4*)(src + 4);
  u16x8 o;
  o[0] = f2bf(v0.x); o[1] = f2bf(v0.y); o[2] = f2bf(v0.z); o[3] = f2bf(v0.w);
  o[4] = f2bf(v1.x); o[5] = f2bf(v1.y); o[6] = f2bf(v1.z); o[7] = f2bf(v1.w);
  *(u16x8*)(Wf + (size_t)idx * 8u) = o;
}

// ---------------- prep: state ----------------
__global__ __launch_bounds__(256) void prep_state_kernel(
    const float* __restrict__ h0a, const float* __restrict__ h0b,
    const float* __restrict__ c0a, const float* __restrict__ c0b,
    const float* __restrict__ b_ih, const float* __restrict__ b_hh,
    const int* __restrict__ batch_a, const int* __restrict__ batch_b,
    const float* __restrict__ emb,
    float* __restrict__ bias, u16* __restrict__ hb0, float* __restrict__ cb,
    u16* __restrict__ xb0) {
  unsigned i = blockIdx.x * 256u + threadIdx.x;
  unsigned r = i >> 10;
  unsigned k = i & 1023u;
  float hv = (r < 128u) ? h0a[i] : h0b[i - 131072u];
  float cv = (r < 128u) ? c0a[i] : c0b[i - 131072u];
  hb0[i] = f2bf(hv);
  cb[i] = cv;
  int token = (r < 128u) ? batch_a[r] : batch_b[r - 128u];
  xb0[i] = f2bf(emb[(size_t)token * 1024u + k]);
  if (i < 4096u) bias[i] = b_ih[i] + b_hh[i];
}

// ---------------- the recurrent step ----------------
// grid 256 = 4 M-tiles x 64 NH-tiles; block 512 = 8 waves: kg(2) x wm(2) x wn(2).
// A (x|h) staged in swizzled double-buffered LDS; B-frags direct from Wf (L2).
__global__ __launch_bounds__(512) void lstm_step_kernel(
    const int* __restrict__ batch_a, const int* __restrict__ batch_b,
    const float* __restrict__ emb, const u16* __restrict__ Wf,
    const float* __restrict__ bias,
    const u16* __restrict__ x_in, u16* __restrict__ x_next,
    const u16* __restrict__ h_in, u16* __restrict__ h_out,
    float* __restrict__ cbuf, int t) {
  __shared__ u16 As[2][2][64][128];   // [kg][buf][row][k], 256B rows, XOR-swizzled
  __shared__ float Gs[64][68];

  const int tid = threadIdx.x;
  const int lane = tid & 63;
  const int w = tid >> 6;
  const int wm = (w >> 1) & 1, wn = w & 1, kg = w >> 2;
  const int m = blockIdx.x >> 6;
  const int nh = blockIdx.x & 63;

  // x_{t+1} pre-gather: issue loads now (latency hides under GEMM), store at end
  float4 g0 = {0, 0, 0, 0}, g1 = {0, 0, 0, 0};
  const bool do_gather = (t + 1 < 128) && (tid < 128);
  if (do_gather) {
    int r = blockIdx.x;
    int token = (r < 128) ? batch_a[(t + 1) * 128 + r]
                          : batch_b[(t + 1) * 128 + (r - 128)];
    const float* esrc = emb + (size_t)token * 1024 + tid * 8;
    g0 = *(const float4*)esrc;
    g1 = *(const float4*)(esrc + 4);
  }

  // A staging map: group = 256 threads (kg half). thread -> (row, 32-elem chunk)
  const int gtid = tid & 255;
  const int srow = gtid >> 2;          // 0..63
  const int scol = (gtid & 3) << 5;    // elems: 0,32,64,96
  const int wswz = (srow & 7) << 4;    // write swizzle (bytes)
  const u16* aBase = (kg == 0 ? x_in : h_in) + ((size_t)(m * 64 + srow) << 10) + scol;

  // B fragment base pointers (fragment-ordered Wf; 512 elems per frag)
  const u16* wf0 = Wf + ((((size_t)(nh * 4 + wn * 2) * 64) + kg * 32) << 9) + lane * 8;
  const u16* wf1 = wf0 + (64 << 9);

  f32x4 acc[2][2];
#pragma unroll
  for (int a_ = 0; a_ < 2; ++a_)
#pragma unroll
    for (int b_ = 0; b_ < 2; ++b_) acc[a_][b_] = (f32x4){0.f, 0.f, 0.f, 0.f};

  const int fr = lane & 15;
  const int fkb = (lane >> 4) << 4;    // k sub-offset in BYTES: 0,16,32,48
  const int Ra0 = wm * 32 + fr;
  const int Ra1 = Ra0 + 16;
  const int rswz = (fr & 7) << 4;      // read swizzle (same for Ra0/Ra1: &7 eq)
  const char* A0 = (const char*)&As[kg][0][0][0];
  const char* A1 = (const char*)&As[kg][1][0][0];

  // preload it=0
  u16x8 ar[4];
  s16x8 brc[8], brn[8];
#pragma unroll
  for (int q = 0; q < 4; ++q) ar[q] = *(const u16x8*)(aBase + q * 8);
#pragma unroll
  for (int kcl = 0; kcl < 4; ++kcl) {
    brc[kcl * 2]     = *(const s16x8*)(wf0 + (kcl << 9));
    brc[kcl * 2 + 1] = *(const s16x8*)(wf1 + (kcl << 9));
  }

#pragma unroll
  for (int it = 0; it < 8; ++it) {
    {  // stage A tile for this iter (swizzled, bank-balanced)
      char* dst = (char*)&As[kg][it & 1][0][0] + srow * 256;
#pragma unroll
      for (int q = 0; q < 4; ++q)
        *(u16x8*)(dst + ((scol * 2 + q * 16) ^ wswz)) = ar[q];
    }
    __syncthreads();
    if (it < 7) {  // prefetch next A (global std layout) + next B frags (Wf)
      const u16* an = aBase + (it + 1) * 128;
#pragma unroll
      for (int q = 0; q < 4; ++q) ar[q] = *(const u16x8*)(an + q * 8);
#pragma unroll
      for (int kcl = 0; kcl < 4; ++kcl) {
        brn[kcl * 2]     = *(const s16x8*)(wf0 + (((it + 1) * 4 + kcl) << 9));
        brn[kcl * 2 + 1] = *(const s16x8*)(wf1 + (((it + 1) * 4 + kcl) << 9));
      }
    }
    const char* ab = (it & 1) ? A1 : A0;
#pragma unroll
    for (int kcl = 0; kcl < 4; ++kcl) {
      s16x8 af0 = *(const s16x8*)(ab + Ra0 * 256 + ((kcl * 64 + fkb) ^ rswz));
      s16x8 af1 = *(const s16x8*)(ab + Ra1 * 256 + ((kcl * 64 + fkb) ^ rswz));
      acc[0][0] = __builtin_amdgcn_mfma_f32_16x16x32_bf16(af0, brc[kcl * 2],     acc[0][0], 0, 0, 0);
      acc[0][1] = __builtin_amdgcn_mfma_f32_16x16x32_bf16(af0, brc[kcl * 2 + 1], acc[0][1], 0, 0, 0);
      acc[1][0] = __builtin_amdgcn_mfma_f32_16x16x32_bf16(af1, brc[kcl * 2],     acc[1][0], 0, 0, 0);
      acc[1][1] = __builtin_amdgcn_mfma_f32_16x16x32_bf16(af1, brc[kcl * 2 + 1], acc[1][1], 0, 0, 0);
    }
    if (it < 7) {
#pragma unroll
      for (int q = 0; q < 8; ++q) brc[q] = brn[q];
    }
  }

  // combine the two K-group partials through Gs, then cell update
  if (kg == 0) {
#pragma unroll
    for (int a_ = 0; a_ < 2; ++a_)
#pragma unroll
      for (int b_ = 0; b_ < 2; ++b_)
#pragma unroll
        for (int r_ = 0; r_ < 4; ++r_)
          Gs[wm * 32 + a_ * 16 + ((lane >> 4) << 2) + r_][wn * 32 + b_ * 16 + fr] =
              acc[a_][b_][r_];
  }
  __syncthreads();
  if (kg == 1) {
#pragma unroll
    for (int a_ = 0; a_ < 2; ++a_)
#pragma unroll
      for (int b_ = 0; b_ < 2; ++b_)
#pragma unroll
        for (int r_ = 0; r_ < 4; ++r_)
          Gs[wm * 32 + a_ * 16 + ((lane >> 4) << 2) + r_][wn * 32 + b_ * 16 + fr] +=
              acc[a_][b_][r_];
  }
  __syncthreads();

  // cell update: 64 rows x 16 units; 512 threads -> 2 units each
  {
    const int row = tid >> 3;
    const int R2 = m * 64 + row;
    const int u0 = (tid & 7) << 1;
#pragma unroll
    for (int uu = 0; uu < 2; ++uu) {
      int u = u0 + uu;
      int gj = nh * 16 + u;
      float iv = Gs[row][u]      + bias[gj];
      float fv = Gs[row][16 + u] + bias[1024 + gj];
      float gv = Gs[row][32 + u] + bias[2048 + gj];
      float ov = Gs[row][48 + u] + bias[3072 + gj];
      size_t ci = (size_t)R2 * 1024 + gj;
      float c_old = cbuf[ci];
      float si = 1.f / (1.f + __expf(-iv));
      float sf = 1.f / (1.f + __expf(-fv));
      float so = 1.f / (1.f + __expf(-ov));
      float cn = sf * c_old + si * tanhf(gv);
      float hn = so * tanhf(cn);
      cbuf[ci] = cn;
      h_out[ci] = f2bf(hn);
    }
  }

  // store the pre-gathered x_{t+1} row (loads issued at kernel top)
  if (do_gather) {
    int r = blockIdx.x;
    u16x8 o;
    o[0] = f2bf(g0.x); o[1] = f2bf(g0.y); o[2] = f2bf(g0.z); o[3] = f2bf(g0.w);
    o[4] = f2bf(g1.x); o[5] = f2bf(g1.y); o[6] = f2bf(g1.z); o[7] = f2bf(g1.w);
    *(u16x8*)(x_next + (size_t)r * 1024 + tid * 8) = o;
  }
}

// ---------------- finalize ----------------
__global__ __launch_bounds__(256) void finalize_kernel(const u16* __restrict__ h,
                                                       float* __restrict__ out) {
  int b = blockIdx.x;
  int tid = threadIdx.x;
  const u16* ha = h + (size_t)b * 1024;
  const u16* hb = h + (size_t)(b + 128) * 1024;
  float s = 0.f;
  for (int j = tid; j < 1024; j += 256) s += fabsf(bf2f(ha[j]) - bf2f(hb[j]));
  __shared__ float red[256];
  red[tid] = s;
  __syncthreads();
  for (int off = 128; off > 0; off >>= 1) {
    if (tid < off) red[tid] += red[tid + off];
    __syncthreads();
  }
  if (tid == 0) out[b] = expf(-red[0]);
}

extern "C" void kernel_launch(void* const* d_in, const int* in_sizes, int n_in,
                              void* d_out, int out_size, void* d_ws, size_t ws_size,
                              hipStream_t stream) {
  const int* batch_a = (const int*)d_in[0];
  const int* batch_b = (const int*)d_in[1];
  const float* h0_a = (const float*)d_in[2];
  const float* c0_a = (const float*)d_in[3];
  const float* h0_b = (const float*)d_in[4];
  const float* c0_b = (const float*)d_in[5];
  const float* emb  = (const float*)d_in[6];
  const float* w_ih = (const float*)d_in[7];
  const float* w_hh = (const float*)d_in[8];
  const float* b_ih = (const float*)d_in[9];
  const float* b_hh = (const float*)d_in[10];

  char* ws = (char*)d_ws;
  u16*   Wf   = (u16*)(ws);                    // 16,777,216 B
  float* bias = (float*)(ws + 16777216);       //     16,384 B
  u16*   xb0  = (u16*)(ws + 16793600);         //    524,288 B
  u16*   xb1  = (u16*)(ws + 17317888);         //    524,288 B
  u16*   hb0  = (u16*)(ws + 17842176);         //    524,288 B
  u16*   hb1  = (u16*)(ws + 18366464);         //    524,288 B
  float* cb   = (float*)(ws + 18890752);       //  1,048,576 B

  prep_wf_kernel<<<4096, 256, 0, stream>>>(w_ih, w_hh, Wf);
  prep_state_kernel<<<1024, 256, 0, stream>>>(h0_a, h0_b, c0_a, c0_b, b_ih, b_hh,
                                              batch_a, batch_b, emb, bias, hb0, cb, xb0);
  u16* xb[2] = {xb0, xb1};
  u16* hb[2] = {hb0, hb1};
  for (int t = 0; t < 128; ++t) {
    lstm_step_kernel<<<256, 512, 0, stream>>>(batch_a, batch_b, emb, Wf, bias,
                                              xb[t & 1], xb[(t + 1) & 1],
                                              hb[t & 1], hb[(t + 1) & 1], cb, t);
  }
  finalize_kernel<<<128, 256, 0, stream>>>(hb[0], (float*)d_out);
}